// Round 7
// baseline (862.487 us; speedup 1.0000x reference)
//
#include <hip/hip_runtime.h>
#include <hip/hip_bf16.h>
#include <stdint.h>

// ---------------------------------------------------------------------------
// B=256 D=28 N=23 F=128 O=64 H=128 Y=7.  NBSEQ=5888 = 184 blocks x 32 seqs.
// R7:
//  kernA: pack output now BLOCK-LINEAR zlin[bd][414] (coalesced stores; R6
//         profile showed 111MB WRITE vs 63MB legit = 16B-scatter line amp).
//  kernB: gathers zlin directly (per-thread const offset + step*414; L2/L3
//         absorbs the transpose), double-buffered XB x-staging (loads issued
//         at L0 start, written to other parity before B1 -> closing barrier
//         dropped: 3 barriers/step), W rows re-permuted so each lane's 4
//         outputs are contiguous j -> b64 h-writes (was 64x ds_write_u16),
//         biases/c-state/x2-sum remain in LDS (R6 spill fix).
// ---------------------------------------------------------------------------

#define DB 256
#define DD 28
#define DN 23
#define DF 128
#define DO 64
#define DH 128
#define DY 7
#define NBSEQ (DN*DB)
#define ADJSZ (DB*DD*DN*DN)
#define GBLK 184

// workspace byte offsets
#define WB0_OFF   47480832u            // zlin = 7168*414*16 = 47,480,832
#define WB1_OFF   47710208u
#define GWT_OFFB  47972352u

using v8bf  = __attribute__((ext_vector_type(8))) __bf16;
using f32x4 = __attribute__((ext_vector_type(4))) float;
using u32x4 = __attribute__((ext_vector_type(4))) unsigned int;

__device__ __forceinline__ float fsig(float x)  { return 1.f/(1.f+__expf(-x)); }
__device__ __forceinline__ float ftanh(float x) { return 1.f - 2.f/(__expf(2.f*x)+1.f); }

__device__ __forceinline__ unsigned short f2bf(float f){
    unsigned u = __builtin_bit_cast(unsigned, f);
    return (unsigned short)((u + 0x7FFFu + ((u>>16)&1u)) >> 16);
}
__device__ __forceinline__ float bf2f(unsigned short b){
    return __builtin_bit_cast(float, (unsigned)b << 16);
}
__device__ __forceinline__ uint4 ntload4(const uint4* p){
    u32x4 v = __builtin_nontemporal_load((const u32x4*)p);
    return *(uint4*)&v;
}

#define FMA4(xv, wv, a) fmaf((xv).w,(wv).w, fmaf((xv).z,(wv).z, fmaf((xv).y,(wv).y, fmaf((xv).x,(wv).x,(a)))))
#define MFMA_(acc_, A_, B_) acc_ = __builtin_amdgcn_mfma_f32_16x16x32_bf16(A_, B_, acc_, 0, 0, 0)

// ---------------------------------------------------------------------------
// Prep.  Wb[kt][mt][lane][e].  A-frag row rit=lane&15 -> (lj=rit>>2, g=rit&3).
// j-REMAP (R7): orig row r = g*128 + (mt>>2)*16 + lj*4 + (mt&3)
//   => at runtime j = 16w + lhi*4 + mi  (lane's 4 mi outputs contiguous).
// k = kt*32 + (lane>>4)*8 + e.
// L0 cols: k<65 -> wih0 ; 72<=k<200 -> whh0[k-72] ; else 0.
// L1 cols: k<128 -> wih1 ; else whh1[k-128].
// ---------------------------------------------------------------------------
__global__ __launch_bounds__(256) void kernPrep(
    const float* __restrict__ wih0, const float* __restrict__ whh0,
    const float* __restrict__ wih1, const float* __restrict__ whh1,
    const float* __restrict__ gcn_w,
    unsigned short* __restrict__ wb0, unsigned short* __restrict__ wb1,
    float* __restrict__ gwt)
{
    int idx = blockIdx.x*256 + threadIdx.x;
    if (idx < 114688){
        int e = idx&7, l = (idx>>3)&63, mt = (idx>>9)&31, kt = idx>>14;
        int rit = l&15, lj = rit>>2, g = rit&3;
        int r = g*128 + (mt>>2)*16 + lj*4 + (mt&3);
        int k = kt*32 + (l>>4)*8 + e;
        float v = 0.f;
        if (k < 65)                  v = wih0[r*65 + k];
        else if (k >= 72 && k < 200) v = whh0[r*128 + (k-72)];
        wb0[idx] = f2bf(v);
        return;
    }
    idx -= 114688;
    if (idx < 131072){
        int e = idx&7, l = (idx>>3)&63, mt = (idx>>9)&31, kt = idx>>14;
        int rit = l&15, lj = rit>>2, g = rit&3;
        int r = g*128 + (mt>>2)*16 + lj*4 + (mt&3);
        int k = kt*32 + (l>>4)*8 + e;
        float v = (k < 128) ? wih1[r*128 + k] : whh1[r*128 + (k-128)];
        wb1[idx] = f2bf(v);
        return;
    }
    idx -= 131072;
    if (idx < 8192){
        int o = idx >> 7, f = idx & 127;
        gwt[idx] = gcn_w[f*DO + o];
    }
}

// ---------------------------------------------------------------------------
// Kernel A: per-(b,d) graph stage.  grid = 7168, block = 256.
// Output zlin[bd][414]: p = n*18 + hsel*9 + k8, coalesced 16B stores.
// ---------------------------------------------------------------------------
__global__ __launch_bounds__(256) void kernA(
    const float* __restrict__ x, const float* __restrict__ adj_real,
    const float* __restrict__ infection, const int* __restrict__ day_order,
    const float* __restrict__ w1, const float* __restrict__ b1,
    const float* __restrict__ w2, const float* __restrict__ b2,
    const float* __restrict__ glp, const float* __restrict__ vvec,
    const float* __restrict__ gwt,
    float* __restrict__ out_adj, uint4* __restrict__ zlin4)
{
    const int bd = blockIdx.x;
    const int b  = bd / DD;
    const int t  = threadIdx.x;

    __shared__ float sm[11776];
    const int XS=0, N1=3036, N2=6072, S12=9108, ADJ=9660, XW=10212,
              DEG=11684, DINV=11707, FACT=11730, INFS=11753;
    const int XWP = N1;
    const int GC  = N1;

    const float* xg = x + (size_t)bd * (DN*DF);
    for (int p = t; p < DN*DF; p += 256) {
        int n = p >> 7, f = p & 127;
        sm[XS + n*132 + f] = xg[p];
    }
    if (t < DN) {
        float vv = vvec[t];
        sm[FACT + t] = __expf(vv*vv*(float)day_order[b]);
        sm[INFS + t] = infection[(size_t)bd*DN + t];
    }
    __syncthreads();

    {
        const int mat = t >> 7, fo = t & 127;
        const float* wr = (mat ? w2 : w1) + fo*DF;
        const float bias = (mat ? b2 : b1)[fo];
        float acc[DN];
        #pragma unroll
        for (int n=0;n<DN;n++) acc[n]=0.f;
        float4 w4 = *(const float4*)wr;
        for (int k4=0;k4<32;k4++){
            float4 wn = w4;
            if (k4 < 31) wn = *(const float4*)(wr + 4*(k4+1));
            #pragma unroll
            for (int n=0;n<DN;n++){
                float4 xv = *(const float4*)&sm[XS + n*132 + 4*k4];
                acc[n] = FMA4(xv, w4, acc[n]);
            }
            w4 = wn;
        }
        const int dst = mat ? N2 : N1;
        #pragma unroll
        for (int n=0;n<DN;n++) sm[dst + n*132 + fo] = ftanh(acc[n]+bias);
    }
    __syncthreads();

    if (t < DN) {
        const float* ar = adj_real + (size_t)bd*(DN*DN) + t*DN;
        float s = 0.f;
        for (int m=0;m<DN;m++) s += ar[m];
        sm[DEG+t] = s;
    }
    for (int p=t; p<DN*DN; p+=256){
        int i = p/DN, j = p - i*DN;
        float a = 0.f;
        for (int k4=0;k4<32;k4++){
            float4 av = *(const float4*)&sm[N1 + i*132 + 4*k4];
            float4 bv = *(const float4*)&sm[N2 + j*132 + 4*k4];
            a = FMA4(av, bv, a);
        }
        sm[S12 + i*24 + j] = a;
    }
    __syncthreads();

    for (int p=t; p<DN*DN; p+=256){
        int i=p/DN, j=p-i*DN;
        float al  = fmaxf(ftanh(sm[S12+i*24+j]-sm[S12+j*24+i]), 0.f);
        float md  = fsig(glp[i*DN+j]*sm[DEG+i]*sm[DEG+j]);
        float arv = adj_real[(size_t)bd*(DN*DN) + p];
        float adjv = al + md*arv;
        __builtin_nontemporal_store(adjv, &out_adj[(size_t)bd*(DN*DN) + p]);
        sm[ADJ + i*24 + j] = adjv + (i==j ? 1.f : 0.f);
    }
    __syncthreads();

    if (t<DN){
        float rs=0.f;
        for (int jj=0;jj<DN;jj++) rs += sm[ADJ+t*24+jj];
        sm[DINV+t] = rsqrtf(rs);
    }
    __syncthreads();
    for (int p=t;p<DN*DN;p+=256){
        int i=p/DN, j=p-i*DN;
        sm[ADJ+i*24+j] *= sm[DINV+i]*sm[DINV+j];
    }
    __syncthreads();

    {
        const int o = t & 63, q = t >> 6;
        float acc[DN];
        #pragma unroll
        for (int n=0;n<DN;n++) acc[n]=0.f;
        const float* gw = gwt + o*DF + q*32;
        for (int k4=0;k4<8;k4++){
            float4 w4 = *(const float4*)(gw + 4*k4);
            #pragma unroll
            for (int n=0;n<DN;n++){
                float4 xv = *(const float4*)&sm[XS + n*132 + q*32 + 4*k4];
                acc[n] = FMA4(xv, w4, acc[n]);
            }
        }
        #pragma unroll
        for (int n=0;n<DN;n++) sm[XWP + (q*DN+n)*64 + o] = acc[n];
    }
    __syncthreads();
    for (int p=t;p<DN*64;p+=256){
        int n=p>>6, o=p&63;
        sm[XW+p] = sm[XWP + n*64 + o] + sm[XWP + (DN+n)*64 + o]
                 + sm[XWP + (2*DN+n)*64 + o] + sm[XWP + (3*DN+n)*64 + o];
    }
    __syncthreads();

    for (int p=t;p<DN*64;p+=256){
        int n=p>>6, o=p&63;
        float a=0.f;
        #pragma unroll
        for (int m=0;m<DN;m++) a = fmaf(sm[ADJ+n*24+m], sm[XW+m*64+o], a);
        sm[GC + p] = fmaxf(a,0.f)*sm[FACT+n];
    }
    __syncthreads();

    // pack -> zlin[bd][414], p = n*18 + hsel*9 + k8  (coalesced)
    for (int p=t; p<DN*18; p+=256){
        int n = p/18, r = p - n*18, hsel = r/9, k8 = r - hsel*9;
        __align__(16) unsigned short ob[8];
        #pragma unroll
        for (int e=0;e<8;e++){
            int k = k8*8+e;
            float v = (k<64) ? sm[GC + n*64 + k] : ((k==64) ? sm[INFS+n] : 0.f);
            unsigned short hb = f2bf(v);
            ob[e] = hsel ? f2bf(v - bf2f(hb)) : hb;
        }
        zlin4[(size_t)bd*414 + p] = *(const uint4*)ob;
    }
}

// ---------------------------------------------------------------------------
// Kernel B: MFMA LSTM.  grid=184, block=512 (8 waves).
// Lane: lhi=l>>4, llo=l&15.  acc[mi][nt] gates (i,f,g,o) of j=16w+lhi*4+mi,
// seq=nt*16+llo.  LDS: XB double-buffered x, H0 (L0's h0 + pad), U1 [h0|h1],
// c-states/x2/biases in LDS.  3 barriers/step (enc), +1 for mean/FC.
// ---------------------------------------------------------------------------
#define XB0O 0
#define XB1O 9216
#define H0O  18432          // 2 hsel x 19 k8 x 32 seq x 16B = 19456
#define U1O  37888          // 2 hsel x 32 k8 x 32 seq x 16B = 32768
#define C0O  70656          // 8 slots x 512 f32
#define C1O  87040
#define X2O  103424         // [e][288] f32
#define B0O  112640
#define B1O  114688
#define FCO  116736         // 129 f32
#define INO  117264         // 32 f32
// end 117392

__global__ __launch_bounds__(512, 1) void kernB(
    const uint4* __restrict__ zlin, const v8bf* __restrict__ w0p, const v8bf* __restrict__ w1p,
    const float* __restrict__ b0g, const float* __restrict__ b1g,
    const float* __restrict__ infection, const float* __restrict__ fcw,
    const float* __restrict__ fcb, float* __restrict__ outy)
{
    const int t = threadIdx.x, blk = blockIdx.x;
    const int w = t>>6, l = t&63;
    const int lhi = l>>4, llo = l&15;
    __shared__ __align__(16) unsigned char smraw[117392];
    char* smb = (char*)smraw;

    // zero H0..X2 end (18432..112640)
    {
        uint4 z; z.x=z.y=z.z=z.w=0u;
        for (int i = t; i < (112640-18432)/16; i += 512) ((uint4*)(smb+18432))[i] = z;
    }
    ((float*)(smb+B0O))[t] = b0g[t];
    ((float*)(smb+B1O))[t] = b1g[t];
    if (t < 129) ((float*)(smb+FCO))[t] = (t<128) ? fcw[t] : fcb[0];
    if (t < 32){
        int gseq = blk*32 + t, n = gseq>>8, bb = gseq&255;
        float a = 0.f;
        for (int dd=0; dd<DD; dd++)
            a = fmaf(fcw[128+dd], infection[((size_t)bb*DD+dd)*DN+n], a);
        ((float*)(smb+INO))[t] = a;
    }

    // per-thread staging constants: units u1 = w*72+l, u2 = u1+64 (l<8 only)
    int u1 = w*72 + l;
    int u2 = u1 + 64;
    int hs1 = (u1 >= 288) ? 1 : 0;  int rm1 = u1 - hs1*288;
    int hs2 = (u2 >= 288) ? 1 : 0;  int rm2 = u2 - hs2*288;
    int k81 = rm1 >> 5, sq1 = rm1 & 31;
    int k82 = rm2 >> 5, sq2 = rm2 & 31;
    int gs1 = blk*32 + sq1, gs2 = blk*32 + sq2;
    size_t cb1 = (size_t)(gs1 & 255)*DD*414 + (gs1>>8)*18 + hs1*9 + k81;
    size_t cb2 = (size_t)(gs2 & 255)*DD*414 + (gs2>>8)*18 + hs2*9 + k82;
    int d1 = u1*16, d2 = u2*16;

    __syncthreads();

    // prologue: stage x(0) into XB0
    {
        uint4 a0 = ntload4(zlin + cb1);
        *(uint4*)(smb + XB0O + d1) = a0;
        if (l < 8){
            uint4 a1 = ntload4(zlin + cb2);
            *(uint4*)(smb + XB0O + d2) = a1;
        }
    }
    __syncthreads();

    const float* bias0L = (const float*)(smb+B0O);
    const float* bias1L = (const float*)(smb+B1O);

    for (int step = 0; step < DD + DY; ++step){
        const int xb  = (step & 1) ? XB1O : XB0O;
        const int xbn = (step & 1) ? XB0O : XB1O;
        const bool do_stage = (step + 1 < DD);

        // ---------------- L0 MFMA (+ stage x(step+1)) ----------------
        {
            uint4 sv0, sv1; sv0.x=sv0.y=sv0.z=sv0.w=0u; sv1 = sv0;
            if (do_stage){
                const uint4* sp = zlin + (size_t)(step+1)*414;
                sv0 = ntload4(sp + cb1);
                if (l < 8) sv1 = ntload4(sp + cb2);
            }
            f32x4 acc[4][2];
            #pragma unroll
            for (int mi=0;mi<4;mi++){
                int j = 16*w + lhi*4 + mi;
                f32x4 a;
                a[0]=bias0L[j]; a[1]=bias0L[128+j]; a[2]=bias0L[256+j]; a[3]=bias0L[384+j];
                acc[mi][0] = a; acc[mi][1] = a;
            }
            #pragma unroll
            for (int kt=0; kt<7; ++kt){
                const v8bf* wrow = w0p + (size_t)(kt*32 + w*4)*64 + l;
                v8bf A0 = wrow[0], A1 = wrow[64], A2 = wrow[128], A3 = wrow[192];
                int k8 = kt*4 + lhi;
                bool inx = (k8 <= 8);
                const char* hib = inx ? (smb + xb + k8*512) : (smb + H0O + (k8-9)*512);
                int losh = inx ? 4608 : 9728;
                v8bf BH0 = *(const v8bf*)(hib + llo*16);
                v8bf BH1 = *(const v8bf*)(hib + 256 + llo*16);
                v8bf BL0 = *(const v8bf*)(hib + losh + llo*16);
                v8bf BL1 = *(const v8bf*)(hib + losh + 256 + llo*16);
                MFMA_(acc[0][0], A0, BH0); MFMA_(acc[0][0], A0, BL0);
                MFMA_(acc[1][0], A1, BH0); MFMA_(acc[1][0], A1, BL0);
                MFMA_(acc[2][0], A2, BH0); MFMA_(acc[2][0], A2, BL0);
                MFMA_(acc[3][0], A3, BH0); MFMA_(acc[3][0], A3, BL0);
                MFMA_(acc[0][1], A0, BH1); MFMA_(acc[0][1], A0, BL1);
                MFMA_(acc[1][1], A1, BH1); MFMA_(acc[1][1], A1, BL1);
                MFMA_(acc[2][1], A2, BH1); MFMA_(acc[2][1], A2, BL1);
                MFMA_(acc[3][1], A3, BH1); MFMA_(acc[3][1], A3, BL1);
            }
            if (do_stage){
                *(uint4*)(smb + xbn + d1) = sv0;
                if (l < 8) *(uint4*)(smb + xbn + d2) = sv1;
            }
            __syncthreads();   // B1: U0/H0 reads done, h0 may be overwritten

            // ---- ACT L0 -> h0(step); x2 accumulation of x(step)
            if (step < DD && t < 288){
                const unsigned short* hp = (const unsigned short*)(smb + xb + t*16);
                const unsigned short* lp = (const unsigned short*)(smb + xb + 4608 + t*16);
                float* xs = (float*)(smb + X2O);
                #pragma unroll
                for (int e=0;e<8;e++) xs[e*288+t] += bf2f(hp[e]) + bf2f(lp[e]);
            }
            const int j8 = 2*w + (lhi>>1);
            const int sub = (lhi&1)*8;
            #pragma unroll
            for (int nt=0;nt<2;nt++){
                unsigned short hh[4], hl[4];
                #pragma unroll
                for (int mi=0;mi<4;mi++){
                    float* cslot = (float*)(smb + C0O) + (mi*2+nt)*512 + t;
                    f32x4 a = acc[mi][nt];
                    float ii = fsig(a[0]), ff = fsig(a[1]), gg = ftanh(a[2]), oo = fsig(a[3]);
                    float c = ff*cslot[0] + ii*gg;
                    cslot[0] = c;
                    float h = oo*ftanh(c);
                    hh[mi] = f2bf(h);
                    hl[mi] = f2bf(h - bf2f(hh[mi]));
                }
                uint2 ph, pl;
                ph.x = (unsigned)hh[0] | ((unsigned)hh[1]<<16);
                ph.y = (unsigned)hh[2] | ((unsigned)hh[3]<<16);
                pl.x = (unsigned)hl[0] | ((unsigned)hl[1]<<16);
                pl.y = (unsigned)hl[2] | ((unsigned)hl[3]<<16);
                int bo = j8*512 + (nt*16+llo)*16 + sub;
                *(uint2*)(smb + H0O + bo)        = ph;
                *(uint2*)(smb + H0O + 9728 + bo) = pl;
                *(uint2*)(smb + U1O + bo)         = ph;
                *(uint2*)(smb + U1O + 16384 + bo) = pl;
            }
            __syncthreads();   // B2: h0 visible for L1
        }

        // ---------------- L1 MFMA ----------------
        {
            f32x4 acc1[4][2];
            #pragma unroll
            for (int mi=0;mi<4;mi++){
                int j = 16*w + lhi*4 + mi;
                f32x4 a;
                a[0]=bias1L[j]; a[1]=bias1L[128+j]; a[2]=bias1L[256+j]; a[3]=bias1L[384+j];
                acc1[mi][0] = a; acc1[mi][1] = a;
            }
            #pragma unroll
            for (int kt=0; kt<8; ++kt){
                const v8bf* wrow = w1p + (size_t)(kt*32 + w*4)*64 + l;
                v8bf A0 = wrow[0], A1 = wrow[64], A2 = wrow[128], A3 = wrow[192];
                const char* hib = smb + U1O + (kt*4+lhi)*512;
                v8bf BH0 = *(const v8bf*)(hib + llo*16);
                v8bf BH1 = *(const v8bf*)(hib + 256 + llo*16);
                v8bf BL0 = *(const v8bf*)(hib + 16384 + llo*16);
                v8bf BL1 = *(const v8bf*)(hib + 16384 + 256 + llo*16);
                MFMA_(acc1[0][0], A0, BH0); MFMA_(acc1[0][0], A0, BL0);
                MFMA_(acc1[1][0], A1, BH0); MFMA_(acc1[1][0], A1, BL0);
                MFMA_(acc1[2][0], A2, BH0); MFMA_(acc1[2][0], A2, BL0);
                MFMA_(acc1[3][0], A3, BH0); MFMA_(acc1[3][0], A3, BL0);
                MFMA_(acc1[0][1], A0, BH1); MFMA_(acc1[0][1], A0, BL1);
                MFMA_(acc1[1][1], A1, BH1); MFMA_(acc1[1][1], A1, BL1);
                MFMA_(acc1[2][1], A2, BH1); MFMA_(acc1[2][1], A2, BL1);
                MFMA_(acc1[3][1], A3, BH1); MFMA_(acc1[3][1], A3, BL1);
            }
            __syncthreads();   // B3: U1 reads done

            // ---- ACT L1 -> h1(step)
            const int j8 = 2*w + (lhi>>1);
            const int sub = (lhi&1)*8;
            #pragma unroll
            for (int nt=0;nt<2;nt++){
                unsigned short hh[4], hl[4];
                #pragma unroll
                for (int mi=0;mi<4;mi++){
                    float* cslot = (float*)(smb + C1O) + (mi*2+nt)*512 + t;
                    f32x4 a = acc1[mi][nt];
                    float ii = fsig(a[0]), ff = fsig(a[1]), gg = ftanh(a[2]), oo = fsig(a[3]);
                    float c = ff*cslot[0] + ii*gg;
                    cslot[0] = c;
                    float h = oo*ftanh(c);
                    hh[mi] = f2bf(h);
                    hl[mi] = f2bf(h - bf2f(hh[mi]));
                }
                uint2 ph, pl;
                ph.x = (unsigned)hh[0] | ((unsigned)hh[1]<<16);
                ph.y = (unsigned)hh[2] | ((unsigned)hh[3]<<16);
                pl.x = (unsigned)hl[0] | ((unsigned)hl[1]<<16);
                pl.y = (unsigned)hl[2] | ((unsigned)hl[3]<<16);
                int bo = (16+j8)*512 + (nt*16+llo)*16 + sub;
                *(uint2*)(smb + U1O + bo)         = ph;
                *(uint2*)(smb + U1O + 16384 + bo) = pl;
            }
        }

        // ---- step 27: build decoder mean input into BOTH XB buffers
        if (step == DD-1){
            __syncthreads();
            if (t < 288){
                const float* xs = (const float*)(smb + X2O);
                __align__(16) unsigned short hb8[8], lb8[8];
                #pragma unroll
                for (int e=0;e<8;e++){
                    float v = xs[e*288+t] * (1.f/(float)DD);
                    unsigned short h = f2bf(v);
                    hb8[e] = h;
                    lb8[e] = f2bf(v - bf2f(h));
                }
                *(uint4*)(smb + XB0O + t*16)        = *(const uint4*)hb8;
                *(uint4*)(smb + XB0O + 4608 + t*16) = *(const uint4*)lb8;
                *(uint4*)(smb + XB1O + t*16)        = *(const uint4*)hb8;
                *(uint4*)(smb + XB1O + 4608 + t*16) = *(const uint4*)lb8;
            }
        }

        // ---- decoder FC
        if (step >= DD){
            __syncthreads();   // h1(step) visible
            if (t < 256){
                int seq = t>>3, l8 = t&7;
                const unsigned short* uh = (const unsigned short*)(smb+U1O);
                const unsigned short* ul = (const unsigned short*)(smb+U1O+16384);
                const float* fw = (const float*)(smb+FCO);
                float a = 0.f;
                #pragma unroll
                for (int half=0; half<2; ++half){
                    int k8 = 16 + l8*2 + half;
                    int base = (k8*32 + seq)*8;
                    #pragma unroll
                    for (int e=0;e<8;e++){
                        int j = l8*16 + half*8 + e;
                        a = fmaf(fw[j], bf2f(uh[base+e]) + bf2f(ul[base+e]), a);
                    }
                }
                a += __shfl_down(a, 4, 8);
                a += __shfl_down(a, 2, 8);
                a += __shfl_down(a, 1, 8);
                if (l8 == 0){
                    int gseq = blk*32 + seq, n = gseq>>8, bb = gseq&255;
                    float yv = fmaxf(a + ((const float*)(smb+INO))[seq] + fw[128], 0.f);
                    __builtin_nontemporal_store(yv, &outy[((size_t)bb*DY + (step-DD))*DN + n]);
                }
            }
        }
        // no closing barrier: next L0 reads XB[par] (stable) and h0 (B2-protected);
        // lagging FC/mean waves only read regions next step won't write before B1.
    }
}

// ---------------------------------------------------------------------------
extern "C" void kernel_launch(void* const* d_in, const int* in_sizes, int n_in,
                              void* d_out, int out_size, void* d_ws, size_t ws_size,
                              hipStream_t stream)
{
    const float* x         = (const float*)d_in[0];
    const float* adj_real  = (const float*)d_in[1];
    const float* infection = (const float*)d_in[2];
    const int*   day_order = (const int*)  d_in[3];
    const float* gl_w1     = (const float*)d_in[4];
    const float* gl_b1     = (const float*)d_in[5];
    const float* gl_w2     = (const float*)d_in[6];
    const float* gl_b2     = (const float*)d_in[7];
    const float* glp       = (const float*)d_in[8];
    const float* gcn_w     = (const float*)d_in[9];
    const float* vvec      = (const float*)d_in[10];
    const float* wih0      = (const float*)d_in[11];
    const float* whh0      = (const float*)d_in[12];
    const float* b0        = (const float*)d_in[13];
    const float* wih1      = (const float*)d_in[14];
    const float* whh1      = (const float*)d_in[15];
    const float* b1        = (const float*)d_in[16];
    const float* fcw       = (const float*)d_in[17];
    const float* fcb       = (const float*)d_in[18];

    uint8_t* wsb = (uint8_t*)d_ws;
    uint4*          zlin = (uint4*)(wsb);
    unsigned short* wb0  = (unsigned short*)(wsb + WB0_OFF);
    unsigned short* wb1  = (unsigned short*)(wsb + WB1_OFF);
    float*          gwt  = (float*)(wsb + GWT_OFFB);
    float* out_adj = (float*)d_out;
    float* out_y   = out_adj + ADJSZ;

    kernPrep<<<dim3(992), dim3(256), 0, stream>>>(wih0, whh0, wih1, whh1, gcn_w,
                                                  wb0, wb1, gwt);
    kernA<<<dim3(DB*DD), dim3(256), 0, stream>>>(x, adj_real, infection, day_order,
                                                 gl_w1, gl_b1, gl_w2, gl_b2, glp,
                                                 vvec, gwt, out_adj, zlin);
    kernB<<<dim3(GBLK), dim3(512), 0, stream>>>(zlin, (const v8bf*)wb0,
                                                (const v8bf*)wb1, b0, b1, infection,
                                                fcw, fcb, out_y);
}